// Round 9
// baseline (146.996 us; speedup 1.0000x reference)
//
#include <hip/hip_runtime.h>
#include <hip/hip_bf16.h>

// GAT edge-average forward, factored + CSR via atomic-free bucketed counting sort:
//   A = x @ Wf[:, :64]^T            [N,64]  bf16 in ws
//   B = x @ Wf[:, 64:]^T + bf       [N,64]  f32 in d_out (read-then-overwritten)
//   c = x @ Ww[0, :64]              [N]
//   d = x @ Ww[0, 64:] + bw         [N]
//   CSR build (no global atomics):
//     hist:       counts[bucket][blk] via LDS histogram (bucket = tgt>>8)
//     scan:       2-phase exclusive scan (block offsets folded into consumers)
//     part:       packed (src<<8 | tgt&255) scattered to bucket regions (in ws)
//     sort+gather (FUSED): per-bucket LDS counting sort -> LDS edge list +
//                 prefetched a_e = cg[src]; then gather for this block's
//                 64-node slice: acc += relu(A[s]+B[t])*(c[s]+d[t])
//                 GSPLIT=4 blocks per bucket (duplicate cheap sort, split gather)

#define NBLK 200    // edge-chunk blocks for hist/partition
#define CAP  5120   // LDS edge-list capacity per bucket (mean 4096, sigma ~64)
#define GSPLIT 4    // blocks per bucket in fused sort+gather

__global__ __launch_bounds__(256) void gat_pre_hist(
    const float* __restrict__ x, const float* __restrict__ Wf,
    const float* __restrict__ Ww, const float* __restrict__ bf,
    const float* __restrict__ bw,
    __hip_bfloat16* __restrict__ A16, float* __restrict__ B,
    float* __restrict__ cg, float* __restrict__ dg, int N,
    const int* __restrict__ tgt, int* __restrict__ counts,
    int E, int NB, int chunk, int nb1)
{
    __shared__ float w2[64][132];
    __shared__ float xs[64][68];
    __shared__ float ww[128];
    __shared__ float bfs[64];
    __shared__ int   h[256];

    const int tid = threadIdx.x;

    if (blockIdx.x >= nb1) {
        // LDS-histogram of tgt buckets for this edge chunk; plain global writes
        const int k = blockIdx.x - nb1;          // 0..NBLK-1
        h[tid] = 0;
        __syncthreads();
        const int lo = k * chunk;
        const int hi = min(lo + chunk, E);
        for (int e = lo + tid; e < hi; e += 256)
            atomicAdd(&h[tgt[e] >> 8], 1);       // LDS atomic
        __syncthreads();
        if (tid < NB) counts[tid * NBLK + k] = h[tid];
        return;
    }

    for (int f = tid; f < 64 * 128; f += 256) {
        int d  = f >> 7;
        int kk = f & 127;
        w2[kk & 63][(kk >> 6) * 64 + d] = Wf[f];
    }
    if (tid < 128) ww[tid] = Ww[tid];
    if (tid < 64)  bfs[tid] = bf[tid];

    const int n0 = blockIdx.x << 6;
    for (int i = tid; i < 64 * 64; i += 256) {
        int nl = i >> 6, k = i & 63;
        int n = n0 + nl;
        xs[k][nl] = (n < N) ? x[(size_t)n * 64 + k] : 0.f;
    }
    __syncthreads();

    const int ti = tid & 15, tj = tid >> 4;
    float acc[4][8];
#pragma unroll
    for (int i = 0; i < 4; ++i)
#pragma unroll
        for (int j = 0; j < 8; ++j) acc[i][j] = 0.f;

#pragma unroll 4
    for (int k = 0; k < 64; ++k) {
        const float4 xv = *(const float4*)&xs[k][ti * 4];
        const float4 w0 = *(const float4*)&w2[k][tj * 8];
        const float4 w1 = *(const float4*)&w2[k][tj * 8 + 4];
        const float xa[4] = {xv.x, xv.y, xv.z, xv.w};
        const float wa[8] = {w0.x, w0.y, w0.z, w0.w, w1.x, w1.y, w1.z, w1.w};
#pragma unroll
        for (int i = 0; i < 4; ++i)
#pragma unroll
            for (int j = 0; j < 8; ++j)
                acc[i][j] = fmaf(xa[i], wa[j], acc[i][j]);
    }

#pragma unroll
    for (int i = 0; i < 4; ++i) {
        const int n = n0 + ti * 4 + i;
        if (n < N) {
            if (tj < 8) {
#pragma unroll
                for (int j = 0; j < 8; ++j)
                    A16[(size_t)n * 64 + tj * 8 + j] = __float2bfloat16(acc[i][j]);
            } else {
#pragma unroll
                for (int j = 0; j < 8; ++j) {
                    int d2 = (tj - 8) * 8 + j;
                    B[(size_t)n * 64 + d2] = acc[i][j] + bfs[d2];
                }
            }
        }
    }

    if (tid < 64) {
        const int n = n0 + tid;
        if (n < N) {
            float sc = 0.f, sd = 0.f;
            for (int k = 0; k < 64; ++k) {
                const float xv = xs[k][tid];
                sc = fmaf(xv, ww[k], sc);
                sd = fmaf(xv, ww[64 + k], sd);
            }
            cg[n] = sc;
            dg[n] = sd + bw[0];
        }
    }
}

// Phase 1: per-block exclusive scan (in -> out, may alias), block total -> bsum
__global__ __launch_bounds__(256) void gat_scan1(
    const int* __restrict__ in, int* __restrict__ out,
    int* __restrict__ bsum, int n)
{
    __shared__ int tmp[256];
    const int i = blockIdx.x * 256 + threadIdx.x;
    const int v = (i < n) ? in[i] : 0;
    tmp[threadIdx.x] = v;
    __syncthreads();
#pragma unroll
    for (int off = 1; off < 256; off <<= 1) {
        const int add = (threadIdx.x >= off) ? tmp[threadIdx.x - off] : 0;
        __syncthreads();
        tmp[threadIdx.x] += add;
        __syncthreads();
    }
    if (i < n) out[i] = tmp[threadIdx.x] - v;
    if (threadIdx.x == 255) bsum[blockIdx.x] = tmp[255];
}

// Phase 2: single-block exclusive scan of the <=1024 block sums, in place
__global__ __launch_bounds__(1024) void gat_scan2(int* __restrict__ bsum, int nb)
{
    __shared__ int tmp[1024];
    const int v = (threadIdx.x < nb) ? bsum[threadIdx.x] : 0;
    tmp[threadIdx.x] = v;
    __syncthreads();
#pragma unroll
    for (int off = 1; off < 1024; off <<= 1) {
        const int add = (threadIdx.x >= off) ? tmp[threadIdx.x - off] : 0;
        __syncthreads();
        tmp[threadIdx.x] += add;
        __syncthreads();
    }
    if (threadIdx.x < nb) bsum[threadIdx.x] = tmp[threadIdx.x] - v;
}

// Partition edges into tgt-buckets; psum = counts[i] + bsum[i>>8] (scan3 folded).
// Packed pair: (src << 8) | (tgt & 255). LDS cursors only.
__global__ __launch_bounds__(256) void gat_partition(
    const int* __restrict__ src, const int* __restrict__ tgt,
    const int* __restrict__ counts, const int* __restrict__ bsum,
    unsigned int* __restrict__ pairs, int E, int NB, int chunk)
{
    __shared__ int cur[256];
    const int k = blockIdx.x;
    const int tid = threadIdx.x;
    if (tid < NB) {
        const int idx = tid * NBLK + k;
        cur[tid] = counts[idx] + bsum[idx >> 8];
    }
    __syncthreads();
    const int lo = k * chunk;
    const int hi = min(lo + chunk, E);
    for (int e = lo + tid; e < hi; e += 256) {
        const int t = tgt[e];
        const int s = src[e];
        const int pos = atomicAdd(&cur[t >> 8], 1);   // LDS atomic
        pairs[pos] = ((unsigned int)s << 8) | (unsigned int)(t & 255);
    }
}

// FUSED per-bucket counting sort + gather. GSPLIT blocks per bucket; each
// duplicates the cheap LDS sort (list + prefetched a_e in LDS), then gathers
// its own 64-node slice. B lives in `out` (read-then-overwrite per owner wave).
__global__ __launch_bounds__(256) void gat_sort_gather(
    const unsigned int* __restrict__ pairs, const int* __restrict__ counts,
    const int* __restrict__ bsum, int* __restrict__ gfb,
    const __hip_bfloat16* __restrict__ A16,
    const float* __restrict__ cg, const float* __restrict__ dg,
    float* __restrict__ out, int N, int E, int NB)
{
    __shared__ int   h[256];
    __shared__ int   cur[256];
    __shared__ int   nstart[257];
    __shared__ int   s_lds[CAP];
    __shared__ float ae_lds[CAP];

    const int b   = blockIdx.x / GSPLIT;
    const int sl  = blockIdx.x % GSPLIT;
    const int tid = threadIdx.x;

    const int i0 = b * NBLK;
    const int base = counts[i0] + bsum[i0 >> 8];
    int end = E;
    if (b + 1 < NB) {
        const int i1 = (b + 1) * NBLK;
        end = counts[i1] + bsum[i1 >> 8];
    }
    const int cnt = end - base;
    const bool fits = (cnt <= CAP);

    h[tid] = 0;
    __syncthreads();
    for (int e = base + tid; e < end; e += 256)
        atomicAdd(&h[pairs[e] & 255u], 1);            // LDS atomic
    __syncthreads();
    const int v = h[tid];
#pragma unroll
    for (int off = 1; off < 256; off <<= 1) {
        const int add = (tid >= off) ? h[tid - off] : 0;
        __syncthreads();
        h[tid] += add;
        __syncthreads();
    }
    const int excl = h[tid] - v;                      // exclusive within bucket
    nstart[tid] = excl;
    if (tid == 0) nstart[256] = cnt;
    cur[tid] = excl;
    __syncthreads();

    if (fits) {
        for (int e = base + tid; e < end; e += 256) {
            const unsigned int p = pairs[e];
            const int pos = atomicAdd(&cur[p & 255u], 1);  // LDS atomic
            const int s = (int)(p >> 8);
            s_lds[pos]  = s;
            ae_lds[pos] = cg[s];   // parallel prefetch: kills gather's cg chase
        }
    } else {
        for (int e = base + tid; e < end; e += 256) {
            const unsigned int p = pairs[e];
            const int pos = atomicAdd(&cur[p & 255u], 1);
            gfb[base + pos] = (int)(p >> 8);   // duplicate same-value writes OK
        }
    }
    __syncthreads();

    // gather: this block's slice = nodes [b*256 + sl*64, +64), 16 per wave
    const int d = tid & 63;
    const int w = tid >> 6;
    for (int i = 0; i < 16; ++i) {
        const int nl = sl * 64 + w * 16 + i;
        const int node = (b << 8) + nl;
        if (node >= N) continue;
        const int e0 = nstart[nl];
        const int e1 = nstart[nl + 1];
        const float Bt  = out[(size_t)node * 64 + d];   // B stored in out
        const float dgt = dg[node];
        float acc = 0.f, asum = 0.f;
        if (fits) {
            int e = e0;
            for (; e + 7 < e1; e += 8) {
                int sv[8]; float av[8];
#pragma unroll
                for (int u = 0; u < 8; ++u) { sv[u] = s_lds[e + u]; av[u] = ae_lds[e + u] + dgt; }
#pragma unroll
                for (int u = 0; u < 8; ++u) {
                    const float xv = __bfloat162float(A16[(size_t)sv[u] * 64 + d]);
                    acc = fmaf(fmaxf(xv + Bt, 0.f), av[u], acc);
                    asum += av[u];
                }
            }
            for (; e < e1; ++e) {
                const int s = s_lds[e];
                const float a = ae_lds[e] + dgt;
                const float xv = __bfloat162float(A16[(size_t)s * 64 + d]);
                acc = fmaf(fmaxf(xv + Bt, 0.f), a, acc);
                asum += a;
            }
        } else {
            for (int e = e0; e < e1; ++e) {
                const int s = gfb[base + e];
                const float a = cg[s] + dgt;
                const float xv = __bfloat162float(A16[(size_t)s * 64 + d]);
                acc = fmaf(fmaxf(xv + Bt, 0.f), a, acc);
                asum += a;
            }
        }
        out[(size_t)node * 64 + d] = acc / (asum + 1e-6f);
    }
}

extern "C" void kernel_launch(void* const* d_in, const int* in_sizes, int n_in,
                              void* d_out, int out_size, void* d_ws, size_t ws_size,
                              hipStream_t stream)
{
    // setup_inputs order: x, adj, src, tgt, Msrc, Wf, bf, Ww, bw
    const float* x   = (const float*)d_in[0];
    const int*   src = (const int*)d_in[2];
    const int*   tgt = (const int*)d_in[3];
    const float* Wf  = (const float*)d_in[5];
    const float* bf  = (const float*)d_in[6];
    const float* Ww  = (const float*)d_in[7];
    const float* bw  = (const float*)d_in[8];

    const int N = in_sizes[0] / 64;
    const int E = in_sizes[2];
    float* out = (float*)d_out;

    const int NB    = (N + 255) >> 8;           // 196 buckets (<=256 required)
    const int chunk = (E + NBLK - 1) / NBLK;    // 4000 edges per hist/part block
    const int NBNB  = NB * NBLK;                // 39200 counts

    // B lives in d_out: row read by its owner wave in gat_sort_gather strictly
    // before that wave overwrites it with the output.
    float* B = out;

    __hip_bfloat16* A16 = (__hip_bfloat16*)d_ws;          // N*64 bf16 (6.4 MB)
    float* cg         = (float*)(A16 + (size_t)N * 64);   // N
    float* dg         = cg + N;                           // N
    int*   gfb        = (int*)(dg + N);                   // E (overflow fallback)
    int*   counts     = gfb + E;                          // NBNB (157 KB)
    int*   bsum       = counts + NBNB;                    // <=1024
    unsigned int* pairs = (unsigned int*)(bsum + 1024);   // E u32 (3.2 MB)
    // total ws: ~13.5 MB (well under proven 23.3 MB budget)

    const int nb1 = (N + 63) / 64;
    gat_pre_hist<<<nb1 + NBLK, 256, 0, stream>>>(x, Wf, Ww, bf, bw, A16, B, cg, dg, N,
                                                 tgt, counts, E, NB, chunk, nb1);
    const int nbs = (NBNB + 255) / 256;   // 154 <= 1024
    gat_scan1<<<nbs, 256, 0, stream>>>(counts, counts, bsum, NBNB);
    gat_scan2<<<1, 1024, 0, stream>>>(bsum, nbs);
    gat_partition<<<NBLK, 256, 0, stream>>>(src, tgt, counts, bsum, pairs, E, NB, chunk);
    gat_sort_gather<<<NB * GSPLIT, 256, 0, stream>>>(pairs, counts, bsum, gfb,
                                                     A16, cg, dg, out, N, E, NB);
}

// Round 10
// 93.664 us; speedup vs baseline: 1.5694x; 1.5694x over previous
//
#include <hip/hip_runtime.h>
#include <hip/hip_bf16.h>

// GAT edge-average forward, factored + CSR via atomic-free bucketed counting sort:
//   A = x @ Wf[:, :64]^T            [N,64]  bf16 in ws
//   B = x @ Wf[:, 64:]^T + bf       [N,64]  f32 in d_out (owner-wave read-then-overwrite)
//   c = x @ Ww[0, :64]              [N]
//   d = x @ Ww[0, 64:] + bw         [N]
//   CSR build (no global atomics):
//     hist:   counts[bucket][blk] via LDS histogram (bucket = tgt>>8, NB=196)
//     scan:   2-phase exclusive scan (block offsets folded into consumers)
//     part:   packed (src<<8 | tgt&255) scattered to bucket regions (in ws)
//     bsort:  per-bucket LDS counting sort (1024 thr) -> starts[] +
//             sorted_sa[] = {src, a_e=cg[src]}  (attention scalar prefetched)
//   gather: wave=node, lane=dim, unroll x8, 2-level chain: sorted_sa -> A16 row

#define NBLK 200   // edge-chunk blocks for hist/partition

__global__ __launch_bounds__(256) void gat_pre_hist(
    const float* __restrict__ x, const float* __restrict__ Wf,
    const float* __restrict__ Ww, const float* __restrict__ bf,
    const float* __restrict__ bw,
    __hip_bfloat16* __restrict__ A16, float* __restrict__ B,
    float* __restrict__ cg, float* __restrict__ dg, int N,
    const int* __restrict__ tgt, int* __restrict__ counts,
    int E, int NB, int chunk, int nb1)
{
    __shared__ float w2[64][132];
    __shared__ float xs[64][68];
    __shared__ float ww[128];
    __shared__ float bfs[64];
    __shared__ int   h[256];

    const int tid = threadIdx.x;

    if (blockIdx.x >= nb1) {
        // LDS-histogram of tgt buckets for this edge chunk; plain global writes
        const int k = blockIdx.x - nb1;          // 0..NBLK-1
        h[tid] = 0;
        __syncthreads();
        const int lo = k * chunk;
        const int hi = min(lo + chunk, E);
        for (int e = lo + tid; e < hi; e += 256)
            atomicAdd(&h[tgt[e] >> 8], 1);       // LDS atomic
        __syncthreads();
        if (tid < NB) counts[tid * NBLK + k] = h[tid];
        return;
    }

    for (int f = tid; f < 64 * 128; f += 256) {
        int d  = f >> 7;
        int kk = f & 127;
        w2[kk & 63][(kk >> 6) * 64 + d] = Wf[f];
    }
    if (tid < 128) ww[tid] = Ww[tid];
    if (tid < 64)  bfs[tid] = bf[tid];

    const int n0 = blockIdx.x << 6;
    for (int i = tid; i < 64 * 64; i += 256) {
        int nl = i >> 6, k = i & 63;
        int n = n0 + nl;
        xs[k][nl] = (n < N) ? x[(size_t)n * 64 + k] : 0.f;
    }
    __syncthreads();

    const int ti = tid & 15, tj = tid >> 4;
    float acc[4][8];
#pragma unroll
    for (int i = 0; i < 4; ++i)
#pragma unroll
        for (int j = 0; j < 8; ++j) acc[i][j] = 0.f;

#pragma unroll 4
    for (int k = 0; k < 64; ++k) {
        const float4 xv = *(const float4*)&xs[k][ti * 4];
        const float4 w0 = *(const float4*)&w2[k][tj * 8];
        const float4 w1 = *(const float4*)&w2[k][tj * 8 + 4];
        const float xa[4] = {xv.x, xv.y, xv.z, xv.w};
        const float wa[8] = {w0.x, w0.y, w0.z, w0.w, w1.x, w1.y, w1.z, w1.w};
#pragma unroll
        for (int i = 0; i < 4; ++i)
#pragma unroll
            for (int j = 0; j < 8; ++j)
                acc[i][j] = fmaf(xa[i], wa[j], acc[i][j]);
    }

#pragma unroll
    for (int i = 0; i < 4; ++i) {
        const int n = n0 + ti * 4 + i;
        if (n < N) {
            if (tj < 8) {
#pragma unroll
                for (int j = 0; j < 8; ++j)
                    A16[(size_t)n * 64 + tj * 8 + j] = __float2bfloat16(acc[i][j]);
            } else {
#pragma unroll
                for (int j = 0; j < 8; ++j) {
                    int d2 = (tj - 8) * 8 + j;
                    B[(size_t)n * 64 + d2] = acc[i][j] + bfs[d2];
                }
            }
        }
    }

    if (tid < 64) {
        const int n = n0 + tid;
        if (n < N) {
            float sc = 0.f, sd = 0.f;
            for (int k = 0; k < 64; ++k) {
                const float xv = xs[k][tid];
                sc = fmaf(xv, ww[k], sc);
                sd = fmaf(xv, ww[64 + k], sd);
            }
            cg[n] = sc;
            dg[n] = sd + bw[0];
        }
    }
}

// Phase 1: per-block exclusive scan (in -> out, may alias), block total -> bsum
__global__ __launch_bounds__(256) void gat_scan1(
    const int* __restrict__ in, int* __restrict__ out,
    int* __restrict__ bsum, int n)
{
    __shared__ int tmp[256];
    const int i = blockIdx.x * 256 + threadIdx.x;
    const int v = (i < n) ? in[i] : 0;
    tmp[threadIdx.x] = v;
    __syncthreads();
#pragma unroll
    for (int off = 1; off < 256; off <<= 1) {
        const int add = (threadIdx.x >= off) ? tmp[threadIdx.x - off] : 0;
        __syncthreads();
        tmp[threadIdx.x] += add;
        __syncthreads();
    }
    if (i < n) out[i] = tmp[threadIdx.x] - v;
    if (threadIdx.x == 255) bsum[blockIdx.x] = tmp[255];
}

// Phase 2: single-block exclusive scan of the <=1024 block sums, in place
__global__ __launch_bounds__(1024) void gat_scan2(int* __restrict__ bsum, int nb)
{
    __shared__ int tmp[1024];
    const int v = (threadIdx.x < nb) ? bsum[threadIdx.x] : 0;
    tmp[threadIdx.x] = v;
    __syncthreads();
#pragma unroll
    for (int off = 1; off < 1024; off <<= 1) {
        const int add = (threadIdx.x >= off) ? tmp[threadIdx.x - off] : 0;
        __syncthreads();
        tmp[threadIdx.x] += add;
        __syncthreads();
    }
    if (threadIdx.x < nb) bsum[threadIdx.x] = tmp[threadIdx.x] - v;
}

// Partition edges into tgt-buckets; psum = counts[i] + bsum[i>>8] (scan3 folded).
// Packed pair: (src << 8) | (tgt & 255). LDS cursors only.
__global__ __launch_bounds__(256) void gat_partition(
    const int* __restrict__ src, const int* __restrict__ tgt,
    const int* __restrict__ counts, const int* __restrict__ bsum,
    unsigned int* __restrict__ pairs, int E, int NB, int chunk)
{
    __shared__ int cur[256];
    const int k = blockIdx.x;
    const int tid = threadIdx.x;
    if (tid < NB) {
        const int idx = tid * NBLK + k;
        cur[tid] = counts[idx] + bsum[idx >> 8];
    }
    __syncthreads();
    const int lo = k * chunk;
    const int hi = min(lo + chunk, E);
    for (int e = lo + tid; e < hi; e += 256) {
        const int t = tgt[e];
        const int s = src[e];
        const int pos = atomicAdd(&cur[t >> 8], 1);   // LDS atomic
        pairs[pos] = ((unsigned int)s << 8) | (unsigned int)(t & 255);
    }
}

// Per-bucket counting sort (1024 threads): emits starts[] and
// sorted_sa[] = {src, bitcast(cg[src])} — attention scalar prefetched here
// where 196 blocks x 1024 threads hide the random cg latency.
__global__ __launch_bounds__(1024) void gat_bucket_sort(
    const unsigned int* __restrict__ pairs, const int* __restrict__ counts,
    const int* __restrict__ bsum, const float* __restrict__ cg,
    int* __restrict__ starts, int2* __restrict__ sorted_sa,
    int N, int E, int NB)
{
    __shared__ int h[256];
    __shared__ int cur[256];
    const int b = blockIdx.x;
    const int tid = threadIdx.x;
    const int i0 = b * NBLK;
    const int base = counts[i0] + bsum[i0 >> 8];
    int end = E;
    if (b + 1 < NB) {
        const int i1 = (b + 1) * NBLK;
        end = counts[i1] + bsum[i1 >> 8];
    }

    if (tid < 256) h[tid] = 0;
    __syncthreads();
    for (int e = base + tid; e < end; e += 1024)
        atomicAdd(&h[pairs[e] & 255u], 1);            // LDS atomic
    __syncthreads();
    const int v = (tid < 256) ? h[tid] : 0;
#pragma unroll
    for (int off = 1; off < 256; off <<= 1) {
        int add = 0;
        if (tid < 256 && tid >= off) add = h[tid - off];
        __syncthreads();
        if (tid < 256) h[tid] += add;
        __syncthreads();
    }
    if (tid < 256) {
        const int excl = h[tid] - v;                  // exclusive within bucket
        const int node = (b << 8) + tid;
        if (node < N) starts[node] = base + excl;
        if (b == NB - 1 && tid == 0) starts[N] = E;
        cur[tid] = base + excl;
    }
    __syncthreads();
    for (int e = base + tid; e < end; e += 1024) {
        const unsigned int p = pairs[e];
        const int s = (int)(p >> 8);
        const float ae = cg[s];                       // prefetch attention scalar
        const int pos = atomicAdd(&cur[p & 255u], 1); // LDS atomic
        sorted_sa[pos] = make_int2(s, __float_as_int(ae));
    }
}

__global__ __launch_bounds__(256) void gat_gather(
    const int* __restrict__ starts, const int2* __restrict__ sorted_sa,
    const __hip_bfloat16* __restrict__ A16, const float* __restrict__ dg,
    float* __restrict__ out, int N)
{
    const int d = threadIdx.x & 63;
    const int node = blockIdx.x * (blockDim.x >> 6) + (threadIdx.x >> 6);
    if (node >= N) return;
    const int e0 = starts[node];
    const int e1 = starts[node + 1];
    const float Bt  = out[(size_t)node * 64 + d];     // B stored in out (owner wave)
    const float dgt = dg[node];
    float acc = 0.f, asum = 0.f;

    int e = e0;
    // unroll x8: 8 independent 2-level chains (sorted_sa -> A16 row) in flight
    for (; e + 7 < e1; e += 8) {
        int2 sa[8];
#pragma unroll
        for (int u = 0; u < 8; ++u) sa[u] = sorted_sa[e + u];
        float xv[8];
#pragma unroll
        for (int u = 0; u < 8; ++u)
            xv[u] = __bfloat162float(A16[(size_t)sa[u].x * 64 + d]);
#pragma unroll
        for (int u = 0; u < 8; ++u) {
            const float a = __int_as_float(sa[u].y) + dgt;
            acc = fmaf(fmaxf(xv[u] + Bt, 0.f), a, acc);
            asum += a;
        }
    }
    for (; e < e1; ++e) {
        const int2 sa = sorted_sa[e];
        const float a = __int_as_float(sa.y) + dgt;
        const float xv = __bfloat162float(A16[(size_t)sa.x * 64 + d]);
        acc = fmaf(fmaxf(xv + Bt, 0.f), a, acc);
        asum += a;
    }
    out[(size_t)node * 64 + d] = acc / (asum + 1e-6f);
}

extern "C" void kernel_launch(void* const* d_in, const int* in_sizes, int n_in,
                              void* d_out, int out_size, void* d_ws, size_t ws_size,
                              hipStream_t stream)
{
    // setup_inputs order: x, adj, src, tgt, Msrc, Wf, bf, Ww, bw
    const float* x   = (const float*)d_in[0];
    const int*   src = (const int*)d_in[2];
    const int*   tgt = (const int*)d_in[3];
    const float* Wf  = (const float*)d_in[5];
    const float* bf  = (const float*)d_in[6];
    const float* Ww  = (const float*)d_in[7];
    const float* bw  = (const float*)d_in[8];

    const int N = in_sizes[0] / 64;
    const int E = in_sizes[2];
    float* out = (float*)d_out;

    const int NB    = (N + 255) >> 8;           // 196 buckets (<=256 required)
    const int chunk = (E + NBLK - 1) / NBLK;    // 4000 edges per hist/part block
    const int NBNB  = NB * NBLK;                // 39200 counts

    // B lives in d_out: each row read by its owner wave in gat_gather strictly
    // before that wave overwrites it with the final output.
    float* B = out;

    __hip_bfloat16* A16 = (__hip_bfloat16*)d_ws;            // N*64 bf16 (6.4 MB)
    int2*  sorted_sa  = (int2*)(A16 + (size_t)N * 64);      // E int2 (6.4 MB, 8B-aligned)
    unsigned int* pairs = (unsigned int*)(sorted_sa + E);   // E u32  (3.2 MB)
    float* cg         = (float*)(pairs + E);                // N
    float* dg         = cg + N;                             // N
    int*   starts     = (int*)(dg + N);                     // N+1
    int*   counts     = starts + N + 1;                     // NBNB (157 KB)
    int*   bsum       = counts + NBNB;                      // <=1024
    // total ws: ~16.8 MB (< proven 23.3 MB budget)

    const int nb1 = (N + 63) / 64;
    gat_pre_hist<<<nb1 + NBLK, 256, 0, stream>>>(x, Wf, Ww, bf, bw, A16, B, cg, dg, N,
                                                 tgt, counts, E, NB, chunk, nb1);
    const int nbs = (NBNB + 255) / 256;   // 154 <= 1024
    gat_scan1<<<nbs, 256, 0, stream>>>(counts, counts, bsum, NBNB);
    gat_scan2<<<1, 1024, 0, stream>>>(bsum, nbs);
    gat_partition<<<NBLK, 256, 0, stream>>>(src, tgt, counts, bsum, pairs, E, NB, chunk);
    gat_bucket_sort<<<NB, 1024, 0, stream>>>(pairs, counts, bsum, cg,
                                             starts, sorted_sa, N, E, NB);
    const int nb2 = (N + 3) / 4;  // 4 waves (nodes) per 256-thread block
    gat_gather<<<nb2, 256, 0, stream>>>(starts, sorted_sa, A16, dg, out, N);
}